// Round 10
// baseline (292.381 us; speedup 1.0000x reference)
//
#include <hip/hip_runtime.h>
#include <stdint.h>

#define DEV __device__ __forceinline__

typedef unsigned short u16;
typedef __attribute__((ext_vector_type(8))) unsigned short u16x8;
typedef __attribute__((ext_vector_type(8))) short s16x8;   // bf16x8 fragment (4 VGPRs)
typedef __attribute__((ext_vector_type(4))) unsigned short u16x4;
typedef __attribute__((ext_vector_type(4))) float f32x4;

DEV float bf2f(u16 u) { return __uint_as_float(((unsigned)u) << 16); }
DEV u16 f2bf(float f) {
  unsigned u = __float_as_uint(f);
  u += 0x7FFFu + ((u >> 16) & 1u);
  return (u16)(u >> 16);
}
DEV float gelu_exact(float v) { return 0.5f * v * (1.0f + erff(v * 0.70710678118654752f)); }

#define BARF asm volatile("s_barrier" ::: "memory")

// ---------------------------------------------------------------- fused weight transposes (4 in 1)
// wqkv is emitted in pack8 layout Bp[k/8][N][8] (for gemm_bd); others plain [N][K].
__global__ __launch_bounds__(256) void transpose4_f32_bf16(
    const float* __restrict__ wqkv, u16* __restrict__ wqkvP,
    const float* __restrict__ wmsa, u16* __restrict__ wmsaT,
    const float* __restrict__ wh1, u16* __restrict__ wh1T,
    const float* __restrict__ wh2, u16* __restrict__ wh2T) {
  __shared__ float t[32][33];
  const int id = blockIdx.x;
  const float* in; u16* out; int rows, cols, bx, by; int packed = 0;
  if (id < 3072)      { in = wqkv; out = wqkvP; rows = 1024; cols = 3072; bx = id % 96;          by = id / 96; packed = 1; }
  else if (id < 4096) { in = wmsa; out = wmsaT; rows = 1024; cols = 1024; bx = (id - 3072) % 32; by = (id - 3072) / 32; }
  else if (id < 4608) { in = wh1;  out = wh1T;  rows = 1024; cols = 512;  bx = (id - 4096) % 16; by = (id - 4096) / 16; }
  else                { in = wh2;  out = wh2T;  rows = 512;  cols = 1024; bx = (id - 4608) % 32; by = (id - 4608) / 32; }
  const int tx = threadIdx.x, ty = threadIdx.y;
  const int c0 = bx * 32, r0 = by * 32;
#pragma unroll
  for (int i = 0; i < 32; i += 8) t[ty + i][tx] = in[(size_t)(r0 + ty + i) * cols + c0 + tx];
  __syncthreads();
  if (packed) {
    // element (k = r0+tx, n = c0+ty+i) -> out[((k>>3)*cols + n)*8 + (k&7)]
    const int k = r0 + tx;
#pragma unroll
    for (int i = 0; i < 32; i += 8) {
      const int n = c0 + ty + i;
      out[((size_t)(k >> 3) * cols + n) * 8 + (k & 7)] = f2bf(t[tx][ty + i]);
    }
  } else {
#pragma unroll
    for (int i = 0; i < 32; i += 8)
      out[(size_t)(c0 + ty + i) * rows + r0 + tx] = f2bf(t[tx][ty + i]);
  }
}

// ---------------------------------------------------------------- kpack: qkv k-cols -> kp[kd/8][4096][8]
__global__ __launch_bounds__(256) void kpack(const u16* __restrict__ qkv, u16* __restrict__ kp) {
  const int idx = blockIdx.x * 256 + threadIdx.x;   // 4096 rows x 128 ksegs
  const int row = idx >> 7, kseg = idx & 127;
  u16x8 v = *(const u16x8*)(qkv + (size_t)row * 3072 + 1024 + kseg * 8);
  *(u16x8*)(kp + ((size_t)kseg * 4096 + row) * 8) = v;
}

// ---------------------------------------------------------------- vpack: qkv v-cols -> vp[tok/8][1024][8]
__global__ __launch_bounds__(256) void vpack(const u16* __restrict__ qkv, u16* __restrict__ vp) {
  __shared__ u16 t[64][33];
  const int tx = threadIdx.x, ty = threadIdx.y;   // (32, 8)
  const int v0 = blockIdx.x * 32, t0 = blockIdx.y * 64;
#pragma unroll
  for (int j = 0; j < 8; ++j)
    t[ty * 8 + j][tx] = qkv[(size_t)(t0 + ty * 8 + j) * 3072 + 2048 + v0 + tx];
  __syncthreads();
  u16x8 w;
#pragma unroll
  for (int j = 0; j < 8; ++j) w[j] = t[ty * 8 + j][tx];
  *(u16x8*)(vp + ((size_t)(t0 / 8 + ty) * 1024 + (v0 + tx)) * 8) = w;
}

// ---------------------------------------------------------------- layernorm
__global__ __launch_bounds__(256) void layernorm_bf16(
    const float* __restrict__ in, const float* __restrict__ g,
    const float* __restrict__ b, u16* __restrict__ out) {
  const int tid = threadIdx.x;
  const int lane = tid & 63, wid = tid >> 6;
  const size_t base = (size_t)blockIdx.x * 1024;
  const float4 v = ((const float4*)(in + base))[tid];
  float s = v.x + v.y + v.z + v.w;
  float ss = v.x * v.x + v.y * v.y + v.z * v.z + v.w * v.w;
#pragma unroll
  for (int off = 32; off > 0; off >>= 1) {
    s += __shfl_down(s, off);
    ss += __shfl_down(ss, off);
  }
  __shared__ float red[8];
  if (lane == 0) { red[wid] = s; red[4 + wid] = ss; }
  __syncthreads();
  s = red[0] + red[1] + red[2] + red[3];
  ss = red[4] + red[5] + red[6] + red[7];
  const float mu = s * (1.0f / 1024.0f);
  const float inv = rsqrtf(ss * (1.0f / 1024.0f) - mu * mu + 1e-5f);
  const float4 gv = ((const float4*)g)[tid];
  const float4 bv = ((const float4*)b)[tid];
  u16x4 o;
  o.x = f2bf((v.x - mu) * inv * gv.x + bv.x);
  o.y = f2bf((v.y - mu) * inv * gv.y + bv.y);
  o.z = f2bf((v.z - mu) * inv * gv.z + bv.z);
  o.w = f2bf((v.w - mu) * inv * gv.w + bv.w);
  *(u16x4*)(out + base + tid * 4) = o;
}

// ---------------------------------------------------------------- softmax (4096 cols, in-place bf16)
__global__ __launch_bounds__(256) void softmax4096(u16* __restrict__ p) {
  const int tid = threadIdx.x;
  const int lane = tid & 63, wid = tid >> 6;
  u16* row = p + (size_t)blockIdx.x * 4096;
  u16x8 r0 = ((u16x8*)row)[tid * 2];
  u16x8 r1 = ((u16x8*)row)[tid * 2 + 1];
  float v[16];
#pragma unroll
  for (int i = 0; i < 8; ++i) { v[i] = bf2f(r0[i]); v[8 + i] = bf2f(r1[i]); }
  float mx = v[0];
#pragma unroll
  for (int i = 1; i < 16; ++i) mx = fmaxf(mx, v[i]);
#pragma unroll
  for (int off = 32; off > 0; off >>= 1) mx = fmaxf(mx, __shfl_down(mx, off));
  __shared__ float red[8];
  if (lane == 0) red[wid] = mx;
  __syncthreads();
  mx = fmaxf(fmaxf(red[0], red[1]), fmaxf(red[2], red[3]));
  float sum = 0.0f;
#pragma unroll
  for (int i = 0; i < 16; ++i) { v[i] = __expf(v[i] - mx); sum += v[i]; }
#pragma unroll
  for (int off = 32; off > 0; off >>= 1) sum += __shfl_down(sum, off);
  if (lane == 0) red[4 + wid] = sum;
  __syncthreads();
  sum = red[4] + red[5] + red[6] + red[7];
  const float inv = 1.0f / sum;
  u16x8 o0, o1;
#pragma unroll
  for (int i = 0; i < 8; ++i) { o0[i] = f2bf(v[i] * inv); o1[i] = f2bf(v[8 + i] * inv); }
  ((u16x8*)row)[tid * 2] = o0;
  ((u16x8*)row)[tid * 2 + 1] = o1;
}

// ---------------------------------------------------------------- final: out = enc1 + softmax(h2)
__global__ __launch_bounds__(256) void final_softmax_add(
    const float* __restrict__ h2, const float* __restrict__ enc1, float* __restrict__ out) {
  const int tid = threadIdx.x;
  const int lane = tid & 63, wid = tid >> 6;
  const size_t base = (size_t)blockIdx.x * 1024;
  float4 v = ((const float4*)(h2 + base))[tid];
  float mx = fmaxf(fmaxf(v.x, v.y), fmaxf(v.z, v.w));
#pragma unroll
  for (int off = 32; off > 0; off >>= 1) mx = fmaxf(mx, __shfl_down(mx, off));
  __shared__ float red[8];
  if (lane == 0) red[wid] = mx;
  __syncthreads();
  mx = fmaxf(fmaxf(red[0], red[1]), fmaxf(red[2], red[3]));
  v.x = __expf(v.x - mx); v.y = __expf(v.y - mx);
  v.z = __expf(v.z - mx); v.w = __expf(v.w - mx);
  float sum = v.x + v.y + v.z + v.w;
#pragma unroll
  for (int off = 32; off > 0; off >>= 1) sum += __shfl_down(sum, off);
  if (lane == 0) red[4 + wid] = sum;
  __syncthreads();
  sum = red[4] + red[5] + red[6] + red[7];
  const float inv = 1.0f / sum;
  const float4 e = ((const float4*)(enc1 + base))[tid];
  float4 o;
  o.x = e.x + v.x * inv; o.y = e.y + v.y * inv;
  o.z = e.z + v.z * inv; o.w = e.w + v.w * inv;
  ((float4*)(out + base))[tid] = o;
}

// ---------------------------------------------------------------- reduce split-K bf16 partials (attn@v)
__global__ __launch_bounds__(256) void reduce_partials(
    const u16* __restrict__ P, u16* __restrict__ out) {
  const size_t i = ((size_t)blockIdx.x * 256 + threadIdx.x) * 8;
  const size_t S = 4096ull * 1024ull;
  u16x8 p0 = *(const u16x8*)(P + i);
  u16x8 p1 = *(const u16x8*)(P + S + i);
  u16x8 p2 = *(const u16x8*)(P + 2 * S + i);
  u16x8 p3 = *(const u16x8*)(P + 3 * S + i);
  u16x8 o;
#pragma unroll
  for (int j = 0; j < 8; ++j)
    o[j] = f2bf(bf2f(p0[j]) + bf2f(p1[j]) + bf2f(p2[j]) + bf2f(p3[j]));
  *(u16x8*)(out + i) = o;
}

// ---------------------------------------------------------------- 256x128 GEMM, B direct-from-global (pack8)
// C(M,N) = A(M,K) @ B^T where B is pre-packed Bp[k/8][Nb][8] (bf16).
// A staged via LDS (double-buffered, XOR involution -> natural k-order frags).
// B frags loaded global->VGPR, fully coalesced in pack8. LDS traffic halved
// vs both-operand staging (the measured ~30% MfmaUtil wall).
// Per K-tile-64: {stage A(t+1) 4x gl_lds; load B(t+1) 8x dwordx4; vmcnt(12)
// [drains A(t)+B(t)]; barrier; 8x ds_read a-frags; 16 MFMA; lgkm0; barrier}.
// EPI: 0 = *scale, 1 = +bias, 2 = plain. Split-K via nsplit/sliceStride.
template <int EPI>
__global__ __launch_bounds__(512, 2) void gemm_bd(
    const u16* __restrict__ A, int lda, const u16* __restrict__ Bp, int Nb,
    u16* __restrict__ C, int ldc, const float* __restrict__ bias, float scale,
    int K, int nsplit, size_t sliceStride) {
  __shared__ alignas(16) u16 As[2][256 * 64];  // 32 KB per slot
  const int tid = threadIdx.x;
  const int lane = tid & 63;
  const int wid = tid >> 6;
  const int wr = wid >> 1, wc = wid & 1;  // 4M x 2N wave grid, 64x64 per wave

  // bijective XCD swizzle (nwg % 8 == 0 for all our grids)
  const int gx = gridDim.x;
  const int nwg = gx * gridDim.y;
  int wg = blockIdx.y * gx + blockIdx.x;
  wg = (wg & 7) * (nwg >> 3) + (wg >> 3);
  const int by = wg / gx;
  const int bxk = wg % gx;
  const int ks = bxk % nsplit;
  const int bx = bxk / nsplit;
  const int m0 = by * 256, n0 = bx * 128;
  A += (size_t)ks * K;                                       // k-offset in row-major A
  Bp += (size_t)ks * (size_t)(K >> 3) * (size_t)Nb * 8;      // kseg-plane offset
  C += (size_t)ks * sliceStride;

  const u16* Apan = A + (size_t)m0 * lda;
  const size_t bstrideK = (size_t)Nb * 8;  // u16 per kseg plane
  const int hi4 = lane >> 4;
  // per-lane B column base (16B granule): col = n0 + wc*64 + (lane&15) + n*16
  const u16* Bcol = Bp + (size_t)(n0 + wc * 64 + (lane & 15)) * 8;

  // A staging: lane covers (row = rbase + (lane>>3), 16B slot = lane&7);
  // LDS slot s holds global kseg s ^ (row&7) (involution; content reads natural)
  const int sgk = ((lane & 7) ^ ((lane >> 3) & 7)) * 8;
  const int arow_e = (wr * 64 + (lane & 15)) * 64;  // u16 offset of frag row base

  f32x4 acc[4][4];
#pragma unroll
  for (int m = 0; m < 4; ++m)
#pragma unroll
    for (int n = 0; n < 4; ++n) { f32x4 z = {0.f, 0.f, 0.f, 0.f}; acc[m][n] = z; }

  s16x8 b0[4][2], b1[4][2];

  auto STAGE_A = [&](int t, int s) {
#pragma unroll
    for (int i = 0; i < 4; ++i) {
      const int rbase = i * 64 + wid * 8;  // wave-uniform 8-row chunk
      const int row = rbase + (lane >> 3);
      const u16* src = Apan + (size_t)row * lda + t * 64 + sgk;
      __builtin_amdgcn_global_load_lds(
          (const __attribute__((address_space(1))) void*)src,
          (__attribute__((address_space(3))) void*)(&As[s][0] + rbase * 64 + lane * 8),
          16, 0, 0);
    }
  };

  auto LOADB = [&](int t, s16x8 (&bn)[4][2]) {
#pragma unroll
    for (int n = 0; n < 4; ++n)
#pragma unroll
      for (int kk = 0; kk < 2; ++kk)
        bn[n][kk] = *(const s16x8*)(Bcol + (size_t)(t * 8 + kk * 4 + hi4) * bstrideK + n * 128);
  };

  const int NT = K >> 6;  // even (>= 8 for all uses)

  auto BODY = [&](int t, int s, s16x8 (&bc)[4][2], s16x8 (&bn)[4][2]) {
    const int tn = (t + 1 < NT) ? t + 1 : NT - 1;
    STAGE_A(tn, s ^ 1);
    LOADB(tn, bn);
    asm volatile("s_waitcnt vmcnt(12)" ::: "memory");  // A(t)+B(t) landed
    BARF;                                              // A(t) visible to all
    s16x8 a[4][2];
#pragma unroll
    for (int m = 0; m < 4; ++m)
#pragma unroll
      for (int kk = 0; kk < 2; ++kk)
        a[m][kk] = *(const s16x8*)&As[s][arow_e + m * 16 * 64 +
                                         (((kk * 4 + hi4) ^ (lane & 7)) * 8)];
    __builtin_amdgcn_s_setprio(1);
#pragma unroll
    for (int m = 0; m < 4; ++m)
#pragma unroll
      for (int n = 0; n < 4; ++n)
#pragma unroll
        for (int kk = 0; kk < 2; ++kk)
          acc[m][n] = __builtin_amdgcn_mfma_f32_16x16x32_bf16(a[m][kk], bc[n][kk],
                                                              acc[m][n], 0, 0, 0);
    __builtin_amdgcn_s_setprio(0);
    asm volatile("s_waitcnt lgkmcnt(0)" ::: "memory");  // reads drained pre-barrier
    BARF;                                               // slot s now safe to overwrite
  };

  // prologue: A(0)->slot0, B(0)->b0  (12 loads; first BODY's vmcnt(12) drains them)
  STAGE_A(0, 0);
  LOADB(0, b0);

  for (int it = 0; it < (NT >> 1); ++it) {
    BODY(2 * it, 0, b0, b1);
    BODY(2 * it + 1, 1, b1, b0);
  }

  // epilogue (verified mapping: col=lane&15, row=(lane>>4)*4+r)
  const int crow0 = m0 + wr * 64 + (hi4 << 2);
  const int ccol0 = n0 + wc * 64 + (lane & 15);
#pragma unroll
  for (int m = 0; m < 4; ++m) {
#pragma unroll
    for (int n = 0; n < 4; ++n) {
      const int col = ccol0 + n * 16;
      float bia = 0.0f;
      if (EPI == 1) bia = bias[col];
#pragma unroll
      for (int r = 0; r < 4; ++r) {
        const int row = crow0 + m * 16 + r;
        float v = acc[m][n][r];
        if (EPI == 0) v *= scale;
        if (EPI == 1) v += bia;
        C[(size_t)row * ldc + col] = f2bf(v);
      }
    }
  }
}

// ---------------------------------------------------------------- 128x128 pipelined GEMM (small shapes)
// EPI: 3 = +bias +x ->f32 (enc1), 4 = gelu(+bias)->bf16 (h1), 5 = gelu(+bias)->f32 (h2)
template <int EPI>
__global__ __launch_bounds__(256) void gemm_bt(
    const u16* __restrict__ A, int lda, const u16* __restrict__ Bt, int ldb,
    void* __restrict__ Cv, int ldc, const float* __restrict__ bias,
    const float* __restrict__ xres, int ldx, float scale, int K) {
  __shared__ alignas(16) u16 As[3][128 * 32];
  __shared__ alignas(16) u16 Bs[3][128 * 32];
  const int tid = threadIdx.x;
  const int wid = tid >> 6;
  const int lane = tid & 63;

  const int gx = gridDim.x;
  const int nwg = gridDim.x * gridDim.y;
  int wg = blockIdx.y * gx + blockIdx.x;
  wg = (wg & 7) * (nwg >> 3) + (wg >> 3);
  const int m0 = (wg / gx) * 128;
  const int n0 = (wg % gx) * 128;
  const int wr = wid >> 1, wc = wid & 1;

  const int srow = lane >> 2;
  const int sseg = (((lane & 3) ^ ((lane >> 3) & 3))) * 8;

  f32x4 acc[4][4];
#pragma unroll
  for (int m = 0; m < 4; ++m)
#pragma unroll
    for (int n = 0; n < 4; ++n) { f32x4 z = {0.f, 0.f, 0.f, 0.f}; acc[m][n] = z; }

  const int arow = wr * 64 + (lane & 15);
  const int brow = wc * 64 + (lane & 15);
  const int koff = (((lane >> 4) ^ ((lane >> 1) & 3))) * 8;

  const int NT = K >> 5;

  auto STAGE = [&](int kt, int buf) {
    const int k0 = kt * 32;
#pragma unroll
    for (int i = 0; i < 2; ++i) {
      const int r = i * 64 + wid * 16;
      const u16* ga = A + (size_t)(m0 + r + srow) * lda + k0 + sseg;
      const u16* gb = Bt + (size_t)(n0 + r + srow) * ldb + k0 + sseg;
      __builtin_amdgcn_global_load_lds((const __attribute__((address_space(1))) void*)ga,
                                       (__attribute__((address_space(3))) void*)&As[buf][r * 32], 16, 0, 0);
      __builtin_amdgcn_global_load_lds((const __attribute__((address_space(1))) void*)gb,
                                       (__attribute__((address_space(3))) void*)&Bs[buf][r * 32], 16, 0, 0);
    }
  };

  STAGE(0, 0);
  STAGE(1, 1);
  asm volatile("s_waitcnt vmcnt(4)" ::: "memory");
  BARF;

  int cur = 0;
  for (int t = 0; t < NT; ++t) {
    const int kt = (t + 2 < NT) ? (t + 2) : (NT - 1);
    STAGE(kt, (cur + 2) % 3);

    s16x8 a[4], b[4];
#pragma unroll
    for (int m = 0; m < 4; ++m) a[m] = *(const s16x8*)&As[cur][(arow + m * 16) * 32 + koff];
#pragma unroll
    for (int n = 0; n < 4; ++n) b[n] = *(const s16x8*)&Bs[cur][(brow + n * 16) * 32 + koff];
#pragma unroll
    for (int m = 0; m < 4; ++m)
#pragma unroll
      for (int n = 0; n < 4; ++n)
        acc[m][n] = __builtin_amdgcn_mfma_f32_16x16x32_bf16(a[m], b[n], acc[m][n], 0, 0, 0);

    asm volatile("s_waitcnt vmcnt(4)" ::: "memory");
    BARF;
    cur = (cur + 1) % 3;
  }

  const int crow0 = m0 + wr * 64 + ((lane >> 4) << 2);
  const int ccol0 = n0 + wc * 64 + (lane & 15);
#pragma unroll
  for (int m = 0; m < 4; ++m) {
#pragma unroll
    for (int n = 0; n < 4; ++n) {
      const int col = ccol0 + n * 16;
      const float bia = bias[col];
#pragma unroll
      for (int r = 0; r < 4; ++r) {
        const int row = crow0 + m * 16 + r;
        const float v = acc[m][n][r];
        if (EPI == 3) {
          ((float*)Cv)[(size_t)row * ldc + col] = v + bia + xres[(size_t)row * ldx + col];
        } else if (EPI == 4) {
          ((u16*)Cv)[(size_t)row * ldc + col] = f2bf(gelu_exact(v + bia));
        } else {
          ((float*)Cv)[(size_t)row * ldc + col] = gelu_exact(v + bia);
        }
      }
    }
  }
  (void)scale;
}

// ---------------------------------------------------------------- launch
extern "C" void kernel_launch(void* const* d_in, const int* in_sizes, int n_in,
                              void* d_out, int out_size, void* d_ws, size_t ws_size,
                              hipStream_t stream) {
  const float* x     = (const float*)d_in[0];
  const float* w_qkv = (const float*)d_in[1];
  const float* b_qkv = (const float*)d_in[2];
  const float* w_msa = (const float*)d_in[3];
  const float* b_msa = (const float*)d_in[4];
  const float* ln_g  = (const float*)d_in[5];
  const float* ln_b  = (const float*)d_in[6];
  const float* w_h1  = (const float*)d_in[7];
  const float* b_h1  = (const float*)d_in[8];
  const float* w_h2  = (const float*)d_in[9];
  const float* b_h2  = (const float*)d_in[10];

  char* w = (char*)d_ws;
  u16*   qkv   = (u16*)(w + 0);            // 4096x3072 bf16
  u16*   sc    = (u16*)(w + 25165824);     // 4096x4096 bf16 (scores -> attn in place)
  u16*   lnb   = (u16*)(w + 58720256);     // 4096x1024 bf16 (ln1; then vp; then ln2)
  u16*   vp    = (u16*)(w + 58720256);     // pack8 V (time-shares with lnb: ln1 dead after qkv GEMM, ln2 written after attn@v)
  u16*   av    = (u16*)(w + 67108864);     // 4096x1024 bf16
  u16*   kp    = (u16*)(w + 75497472);     // pack8 K  (old vT slot)
  float* enc1  = (float*)(w + 83886080);   // 4096x1024 f32
  u16*   part  = (u16*)(w + 83886080);     // 4x 4096x1024 bf16 split-K partials (dead before enc1)
  u16*   h1    = (u16*)(w + 100663296);    // 4096x512 bf16
  float* h2    = (float*)(w + 104857600);  // 4096x1024 f32
  u16*   wqkvP = (u16*)(w + 121634816);    // pack8 3072x1024 bf16
  u16*   wmsaT = (u16*)(w + 127926272);    // 1024x1024 bf16
  u16*   wh1T  = (u16*)(w + 130023424);    // 512x1024 bf16
  u16*   wh2T  = (u16*)(w + 131072000);    // 1024x512 bf16
  (void)in_sizes; (void)n_in; (void)out_size; (void)ws_size;

  dim3 tb(32, 8);
  transpose4_f32_bf16<<<5120, tb, 0, stream>>>(w_qkv, wqkvP, w_msa, wmsaT,
                                               w_h1, wh1T, w_h2, wh2T);

  // ln1 = LN(x) -> bf16
  layernorm_bf16<<<4096, 256, 0, stream>>>(x, ln_g, ln_b, lnb);
  // qkv = ln1 @ w_qkv + b_qkv -> bf16   (24x16 = 384 blocks)
  gemm_bd<1><<<dim3(24, 16), 512, 0, stream>>>(lnb, 1024, wqkvP, 3072, qkv, 3072,
                                               b_qkv, 1.0f, 1024, 1, 0);
  // pack K and V panels (lnb dead now -> vp reuses its slot)
  kpack<<<2048, 256, 0, stream>>>(qkv, kp);
  vpack<<<dim3(32, 64), tb, 0, stream>>>(qkv, vp);
  // scores = q @ k^T / 8 -> bf16   (32x16 = 512 blocks)
  gemm_bd<0><<<dim3(32, 16), 512, 0, stream>>>(qkv, 3072, kp, 4096, sc, 4096,
                                               nullptr, 0.125f, 1024, 1, 0);
  // softmax rows (in place)
  softmax4096<<<4096, 256, 0, stream>>>(sc);
  // attn @ v: split-K=4 -> bf16 partials ((8 n-tiles x 4 splits) x 16 = 512 blocks)
  gemm_bd<2><<<dim3(32, 16), 512, 0, stream>>>(sc, 4096, vp, 1024, part, 1024,
                                               nullptr, 1.0f, 1024, 4, 4096ull * 1024ull);
  reduce_partials<<<2048, 256, 0, stream>>>(part, av);
  // enc1 = av @ w_msa + b_msa + x -> f32
  gemm_bt<3><<<dim3(8, 32), 256, 0, stream>>>(av, 1024, wmsaT, 1024, enc1, 1024,
                                              b_msa, x, 1024, 1.0f, 1024);
  // ln2 = LN(enc1) -> bf16 (vp dead now)
  layernorm_bf16<<<4096, 256, 0, stream>>>(enc1, ln_g, ln_b, lnb);
  // h1 = gelu(ln2 @ w_h1 + b_h1) -> bf16
  gemm_bt<4><<<dim3(4, 32), 256, 0, stream>>>(lnb, 1024, wh1T, 1024, h1, 512,
                                              b_h1, nullptr, 0, 1.0f, 1024);
  // h2 = gelu(h1 @ w_h2 + b_h2) -> f32
  gemm_bt<5><<<dim3(8, 32), 256, 0, stream>>>(h1, 512, wh2T, 512, h2, 1024,
                                              b_h2, nullptr, 0, 1.0f, 512);
  // out = enc1 + softmax(h2)
  final_softmax_add<<<4096, 256, 0, stream>>>(h2, enc1, (float*)d_out);
}

// Round 11
// 228.059 us; speedup vs baseline: 1.2820x; 1.2820x over previous
//
#include <hip/hip_runtime.h>
#include <stdint.h>

#define DEV __device__ __forceinline__

typedef unsigned short u16;
typedef __attribute__((ext_vector_type(8))) unsigned short u16x8;
typedef __attribute__((ext_vector_type(4))) unsigned short u16x4;
typedef __attribute__((ext_vector_type(4))) float f32x4;

DEV float bf2f(u16 u) { return __uint_as_float(((unsigned)u) << 16); }
DEV u16 f2bf(float f) {
  unsigned u = __float_as_uint(f);
  u += 0x7FFFu + ((u >> 16) & 1u);
  return (u16)(u >> 16);
}
DEV float gelu_exact(float v) { return 0.5f * v * (1.0f + erff(v * 0.70710678118654752f)); }

// fenced workgroup barrier: s_barrier + compiler memory fence
#define BARF asm volatile("s_barrier" ::: "memory")

// ---------------------------------------------------------------- fused weight transposes (4 in 1)
__global__ __launch_bounds__(256) void transpose4_f32_bf16(
    const float* __restrict__ wqkv, u16* __restrict__ wqkvT,
    const float* __restrict__ wmsa, u16* __restrict__ wmsaT,
    const float* __restrict__ wh1, u16* __restrict__ wh1T,
    const float* __restrict__ wh2, u16* __restrict__ wh2T) {
  __shared__ float t[32][33];
  const int id = blockIdx.x;
  const float* in; u16* out; int rows, cols, bx, by;
  if (id < 3072)      { in = wqkv; out = wqkvT; rows = 1024; cols = 3072; bx = id % 96;          by = id / 96; }
  else if (id < 4096) { in = wmsa; out = wmsaT; rows = 1024; cols = 1024; bx = (id - 3072) % 32; by = (id - 3072) / 32; }
  else if (id < 4608) { in = wh1;  out = wh1T;  rows = 1024; cols = 512;  bx = (id - 4096) % 16; by = (id - 4096) / 16; }
  else                { in = wh2;  out = wh2T;  rows = 512;  cols = 1024; bx = (id - 4608) % 32; by = (id - 4608) / 32; }
  const int tx = threadIdx.x, ty = threadIdx.y;
  const int c0 = bx * 32, r0 = by * 32;
#pragma unroll
  for (int i = 0; i < 32; i += 8) t[ty + i][tx] = in[(size_t)(r0 + ty + i) * cols + c0 + tx];
  __syncthreads();
#pragma unroll
  for (int i = 0; i < 32; i += 8)
    out[(size_t)(c0 + ty + i) * rows + r0 + tx] = f2bf(t[tx][ty + i]);
}

__global__ __launch_bounds__(256) void transpose_bf16(
    const u16* __restrict__ in, int ldin, u16* __restrict__ out, int ldout) {
  __shared__ u16 t[32][33];
  const int tx = threadIdx.x, ty = threadIdx.y;
  const int c0 = blockIdx.x * 32, r0 = blockIdx.y * 32;
#pragma unroll
  for (int i = 0; i < 32; i += 8) t[ty + i][tx] = in[(size_t)(r0 + ty + i) * ldin + c0 + tx];
  __syncthreads();
#pragma unroll
  for (int i = 0; i < 32; i += 8)
    out[(size_t)(c0 + ty + i) * ldout + r0 + tx] = t[tx][ty + i];
}

// ---------------------------------------------------------------- layernorm
__global__ __launch_bounds__(256) void layernorm_bf16(
    const float* __restrict__ in, const float* __restrict__ g,
    const float* __restrict__ b, u16* __restrict__ out) {
  const int tid = threadIdx.x;
  const int lane = tid & 63, wid = tid >> 6;
  const size_t base = (size_t)blockIdx.x * 1024;
  const float4 v = ((const float4*)(in + base))[tid];
  float s = v.x + v.y + v.z + v.w;
  float ss = v.x * v.x + v.y * v.y + v.z * v.z + v.w * v.w;
#pragma unroll
  for (int off = 32; off > 0; off >>= 1) {
    s += __shfl_down(s, off);
    ss += __shfl_down(ss, off);
  }
  __shared__ float red[8];
  if (lane == 0) { red[wid] = s; red[4 + wid] = ss; }
  __syncthreads();
  s = red[0] + red[1] + red[2] + red[3];
  ss = red[4] + red[5] + red[6] + red[7];
  const float mu = s * (1.0f / 1024.0f);
  const float inv = rsqrtf(ss * (1.0f / 1024.0f) - mu * mu + 1e-5f);
  const float4 gv = ((const float4*)g)[tid];
  const float4 bv = ((const float4*)b)[tid];
  u16x4 o;
  o.x = f2bf((v.x - mu) * inv * gv.x + bv.x);
  o.y = f2bf((v.y - mu) * inv * gv.y + bv.y);
  o.z = f2bf((v.z - mu) * inv * gv.z + bv.z);
  o.w = f2bf((v.w - mu) * inv * gv.w + bv.w);
  *(u16x4*)(out + base + tid * 4) = o;
}

// ---------------------------------------------------------------- softmax (4096 cols, in-place bf16)
__global__ __launch_bounds__(256) void softmax4096(u16* __restrict__ p) {
  const int tid = threadIdx.x;
  const int lane = tid & 63, wid = tid >> 6;
  u16* row = p + (size_t)blockIdx.x * 4096;
  u16x8 r0 = ((u16x8*)row)[tid * 2];
  u16x8 r1 = ((u16x8*)row)[tid * 2 + 1];
  float v[16];
#pragma unroll
  for (int i = 0; i < 8; ++i) { v[i] = bf2f(r0[i]); v[8 + i] = bf2f(r1[i]); }
  float mx = v[0];
#pragma unroll
  for (int i = 1; i < 16; ++i) mx = fmaxf(mx, v[i]);
#pragma unroll
  for (int off = 32; off > 0; off >>= 1) mx = fmaxf(mx, __shfl_down(mx, off));
  __shared__ float red[8];
  if (lane == 0) red[wid] = mx;
  __syncthreads();
  mx = fmaxf(fmaxf(red[0], red[1]), fmaxf(red[2], red[3]));
  float sum = 0.0f;
#pragma unroll
  for (int i = 0; i < 16; ++i) { v[i] = __expf(v[i] - mx); sum += v[i]; }
#pragma unroll
  for (int off = 32; off > 0; off >>= 1) sum += __shfl_down(sum, off);
  if (lane == 0) red[4 + wid] = sum;
  __syncthreads();
  sum = red[4] + red[5] + red[6] + red[7];
  const float inv = 1.0f / sum;
  u16x8 o0, o1;
#pragma unroll
  for (int i = 0; i < 8; ++i) { o0[i] = f2bf(v[i] * inv); o1[i] = f2bf(v[8 + i] * inv); }
  ((u16x8*)row)[tid * 2] = o0;
  ((u16x8*)row)[tid * 2 + 1] = o1;
}

// ---------------------------------------------------------------- final: out = enc1 + softmax(h2)
__global__ __launch_bounds__(256) void final_softmax_add(
    const float* __restrict__ h2, const float* __restrict__ enc1, float* __restrict__ out) {
  const int tid = threadIdx.x;
  const int lane = tid & 63, wid = tid >> 6;
  const size_t base = (size_t)blockIdx.x * 1024;
  float4 v = ((const float4*)(h2 + base))[tid];
  float mx = fmaxf(fmaxf(v.x, v.y), fmaxf(v.z, v.w));
#pragma unroll
  for (int off = 32; off > 0; off >>= 1) mx = fmaxf(mx, __shfl_down(mx, off));
  __shared__ float red[8];
  if (lane == 0) red[wid] = mx;
  __syncthreads();
  mx = fmaxf(fmaxf(red[0], red[1]), fmaxf(red[2], red[3]));
  v.x = __expf(v.x - mx); v.y = __expf(v.y - mx);
  v.z = __expf(v.z - mx); v.w = __expf(v.w - mx);
  float sum = v.x + v.y + v.z + v.w;
#pragma unroll
  for (int off = 32; off > 0; off >>= 1) sum += __shfl_down(sum, off);
  if (lane == 0) red[4 + wid] = sum;
  __syncthreads();
  sum = red[4] + red[5] + red[6] + red[7];
  const float inv = 1.0f / sum;
  const float4 e = ((const float4*)(enc1 + base))[tid];
  float4 o;
  o.x = e.x + v.x * inv; o.y = e.y + v.y * inv;
  o.z = e.z + v.z * inv; o.w = e.w + v.w * inv;
  ((float4*)(out + base))[tid] = o;
}

// ---------------------------------------------------------------- reduce split-K bf16 partials
__global__ __launch_bounds__(256) void reduce_partials(
    const u16* __restrict__ P, u16* __restrict__ out) {
  const size_t i = ((size_t)blockIdx.x * 256 + threadIdx.x) * 8;
  const size_t S = 4096ull * 1024ull;
  u16x8 p0 = *(const u16x8*)(P + i);
  u16x8 p1 = *(const u16x8*)(P + S + i);
  u16x8 p2 = *(const u16x8*)(P + 2 * S + i);
  u16x8 p3 = *(const u16x8*)(P + 3 * S + i);
  u16x8 o;
#pragma unroll
  for (int j = 0; j < 8; ++j)
    o[j] = f2bf(bf2f(p0[j]) + bf2f(p1[j]) + bf2f(p2[j]) + bf2f(p3[j]));
  *(u16x8*)(out + i) = o;
}

// ---------------------------------------------------------------- 256x256 GEMM, 2-region/iteration (8 waves)
// C(M,N) = A(M,K) @ Bt(N,K)^T, bf16 in, f32 acc, bf16 out.
// EPI: 0 = *scale, 1 = +bias, 2 = plain. Optional split-K via nsplit/sliceStride.
template <int EPI>
__global__ __launch_bounds__(512, 2) void gemm256(
    const u16* __restrict__ A, int lda, const u16* __restrict__ Bt, int ldb,
    u16* __restrict__ C, int ldc, const float* __restrict__ bias, float scale,
    int K, int nsplit, size_t sliceStride) {
  __shared__ alignas(16) u16 As[2][16384];  // 2 slots x 256 rows x 64 k
  __shared__ alignas(16) u16 Bs[2][16384];
  const int tid = threadIdx.x;
  const int wid = tid >> 6;
  const int lane = tid & 63;
  const int wr = wid >> 2, wc = wid & 3;  // 2 x 4 wave grid, per-wave 128x64

  const int gx = gridDim.x;
  const int nwg = gx * gridDim.y;
  int wg = blockIdx.y * gx + blockIdx.x;
  wg = (wg & 7) * (nwg >> 3) + (wg >> 3);
  const int by = wg / gx;
  const int bxk = wg % gx;
  const int ks = bxk % nsplit;
  const int bx = bxk / nsplit;
  const int m0 = by * 256, n0 = bx * 256;
  A += (size_t)ks * K;
  Bt += (size_t)ks * K;
  C += (size_t)ks * sliceStride;

  const u16* Apan = A + (size_t)m0 * lda;
  const u16* Bpan = Bt + (size_t)n0 * ldb;

  const int sgk = ((lane & 7) ^ ((lane >> 3) & 7)) * 8;  // global k elems
  const int hi4 = lane >> 4;
  const int kgo0 = ((0 * 4 + hi4) ^ (lane & 7)) * 8;  // kk=0, u16 offset
  const int kgo1 = ((1 * 4 + hi4) ^ (lane & 7)) * 8;  // kk=1
  const int arowo = (wr * 128 + (lane & 15)) * 64;
  const int browo = (wc * 64 + (lane & 15)) * 64;

  f32x4 acc[8][4];
#pragma unroll
  for (int m = 0; m < 8; ++m)
#pragma unroll
    for (int n = 0; n < 4; ++n) { f32x4 z = {0.f, 0.f, 0.f, 0.f}; acc[m][n] = z; }

  u16x8 a0[2][2], a1[2][2], b[4][2];

#define ST_HALF(dst, pan, ld, t, h)                                              \
  {                                                                              \
    _Pragma("unroll") for (int j = 0; j < 2; ++j) {                              \
      const int chunk = (tid >> 6) * 2 + j;                                      \
      const int row = (h)*128 + chunk * 8 + (lane >> 3);                         \
      const u16* gsrc = (pan) + (size_t)row * (ld) + (t)*64 + sgk;               \
      __builtin_amdgcn_global_load_lds(                                          \
          (const __attribute__((address_space(1))) void*)gsrc,                   \
          (__attribute__((address_space(3))) void*)((dst) + (h)*8192 +           \
                                                    chunk * 512 + lane * 8),     \
          16, 0, 0);                                                             \
    }                                                                            \
  }

#define LOADB(S)                                                                 \
  _Pragma("unroll") for (int n = 0; n < 4; ++n) {                                \
    b[n][0] = *(const u16x8*)&Bs[S][browo + n * 1024 + kgo0];                    \
    b[n][1] = *(const u16x8*)&Bs[S][browo + n * 1024 + kgo1];                    \
  }

#define LOADA(S, Q, DST)                                                         \
  _Pragma("unroll") for (int mi = 0; mi < 2; ++mi) {                             \
    DST[mi][0] = *(const u16x8*)&As[S][arowo + (2 * (Q) + mi) * 1024 + kgo0];    \
    DST[mi][1] = *(const u16x8*)&As[S][arowo + (2 * (Q) + mi) * 1024 + kgo1];    \
  }

#define MFMAQ(SRC, Q)                                                            \
  _Pragma("unroll") for (int mi = 0; mi < 2; ++mi)                               \
      _Pragma("unroll") for (int n = 0; n < 4; ++n)                              \
          _Pragma("unroll") for (int kk = 0; kk < 2; ++kk)                       \
              asm("v_mfma_f32_16x16x32_bf16 %0, %1, %2, %0"                      \
                  : "+v"(acc[2 * (Q) + mi][n])                                   \
                  : "v"(SRC[mi][kk]), "v"(b[n][kk]));

#define VMW asm volatile("s_waitcnt vmcnt(4)" ::: "memory");

  const int NT = K >> 6;
  const int NI = NT >> 1;

  ST_HALF(&Bs[0][0], Bpan, ldb, 0, 0);
  ST_HALF(&Bs[0][0], Bpan, ldb, 0, 1);
  ST_HALF(&As[0][0], Apan, lda, 0, 0);
  ST_HALF(&As[0][0], Apan, lda, 0, 1);
  ST_HALF(&Bs[1][0], Bpan, ldb, 1, 0);
  ST_HALF(&Bs[1][0], Bpan, ldb, 1, 1);
  VMW;
  BARF;

  for (int it = 0; it < NI; ++it) {
    const int t1 = 2 * it + 1;
    const int tS0 = (2 * it + 2 < NT) ? 2 * it + 2 : NT - 1;
    const int tS1 = (2 * it + 3 < NT) ? 2 * it + 3 : NT - 1;

    // ---- region 0: K-tile t0 (slot0) ----
    LOADB(0);
    LOADA(0, 0, a0); LOADA(0, 1, a1);
    __builtin_amdgcn_s_setprio(1);
    MFMAQ(a0, 0); MFMAQ(a1, 1);
    __builtin_amdgcn_s_setprio(0);
    LOADA(0, 2, a0); LOADA(0, 3, a1);
    BARF;
    ST_HALF(&As[1][0], Apan, lda, t1, 0);
    ST_HALF(&As[1][0], Apan, lda, t1, 1);
    ST_HALF(&Bs[0][0], Bpan, ldb, tS0, 0);
    ST_HALF(&Bs[0][0], Bpan, ldb, tS0, 1);
    __builtin_amdgcn_s_setprio(1);
    MFMAQ(a0, 2); MFMAQ(a1, 3);
    __builtin_amdgcn_s_setprio(0);
    VMW;
    BARF;

    // ---- region 1: K-tile t1 (slot1) ----
    LOADB(1);
    LOADA(1, 0, a0); LOADA(1, 1, a1);
    __builtin_amdgcn_s_setprio(1);
    MFMAQ(a0, 0); MFMAQ(a1, 1);
    __builtin_amdgcn_s_setprio(0);
    LOADA(1, 2, a0); LOADA(1, 3, a1);
    BARF;
    ST_HALF(&As[0][0], Apan, lda, tS0, 0);
    ST_HALF(&As[0][0], Apan, lda, tS0, 1);
    ST_HALF(&Bs[1][0], Bpan, ldb, tS1, 0);
    ST_HALF(&Bs[1][0], Bpan, ldb, tS1, 1);
    __builtin_amdgcn_s_setprio(1);
    MFMAQ(a0, 2); MFMAQ(a1, 3);
    __builtin_amdgcn_s_setprio(0);
    VMW;
    BARF;
  }
  asm volatile("s_waitcnt vmcnt(0)" ::: "memory");
  BARF;

  const int crow0 = m0 + wr * 128 + hi4 * 4;
  const int ccol0 = n0 + wc * 64 + (lane & 15);
#pragma unroll
  for (int m = 0; m < 8; ++m) {
#pragma unroll
    for (int n = 0; n < 4; ++n) {
      const int col = ccol0 + n * 16;
      float bia = 0.0f;
      if (EPI == 1) bia = bias[col];
#pragma unroll
      for (int r = 0; r < 4; ++r) {
        const int row = crow0 + m * 16 + r;
        float v = acc[m][n][r];
        if (EPI == 0) v *= scale;
        if (EPI == 1) v += bia;
        C[(size_t)row * ldc + col] = f2bf(v);
      }
    }
  }
#undef ST_HALF
#undef LOADB
#undef LOADA
#undef MFMAQ
#undef VMW
}

// ---------------------------------------------------------------- 128x128 pipelined GEMM (small shapes)
// EPI: 3 = +bias +x ->f32 (enc1), 4 = gelu(+bias)->bf16 (h1), 5 = gelu(+bias)->f32 (h2)
template <int EPI>
__global__ __launch_bounds__(256) void gemm_bt(
    const u16* __restrict__ A, int lda, const u16* __restrict__ Bt, int ldb,
    void* __restrict__ Cv, int ldc, const float* __restrict__ bias,
    const float* __restrict__ xres, int ldx, float scale, int K) {
  __shared__ alignas(16) u16 As[3][128 * 32];
  __shared__ alignas(16) u16 Bs[3][128 * 32];
  const int tid = threadIdx.x;
  const int wid = tid >> 6;
  const int lane = tid & 63;

  const int gx = gridDim.x;
  const int nwg = gridDim.x * gridDim.y;
  int wg = blockIdx.y * gx + blockIdx.x;
  wg = (wg & 7) * (nwg >> 3) + (wg >> 3);
  const int m0 = (wg / gx) * 128;
  const int n0 = (wg % gx) * 128;
  const int wr = wid >> 1, wc = wid & 1;

  const int srow = lane >> 2;
  const int sseg = (((lane & 3) ^ ((lane >> 3) & 3))) * 8;

  f32x4 acc[4][4];
#pragma unroll
  for (int m = 0; m < 4; ++m)
#pragma unroll
    for (int n = 0; n < 4; ++n) { f32x4 z = {0.f, 0.f, 0.f, 0.f}; acc[m][n] = z; }

  const int arow = wr * 64 + (lane & 15);
  const int brow = wc * 64 + (lane & 15);
  const int koff = (((lane >> 4) ^ ((lane >> 1) & 3))) * 8;

  const int NT = K >> 5;

  auto STAGE = [&](int kt, int buf) {
    const int k0 = kt * 32;
#pragma unroll
    for (int i = 0; i < 2; ++i) {
      const int r = i * 64 + wid * 16;
      const u16* ga = A + (size_t)(m0 + r + srow) * lda + k0 + sseg;
      const u16* gb = Bt + (size_t)(n0 + r + srow) * ldb + k0 + sseg;
      __builtin_amdgcn_global_load_lds((const __attribute__((address_space(1))) void*)ga,
                                       (__attribute__((address_space(3))) void*)&As[buf][r * 32], 16, 0, 0);
      __builtin_amdgcn_global_load_lds((const __attribute__((address_space(1))) void*)gb,
                                       (__attribute__((address_space(3))) void*)&Bs[buf][r * 32], 16, 0, 0);
    }
  };

  STAGE(0, 0);
  STAGE(1, 1);
  asm volatile("s_waitcnt vmcnt(4)" ::: "memory");
  BARF;

  int cur = 0;
  for (int t = 0; t < NT; ++t) {
    const int kt = (t + 2 < NT) ? (t + 2) : (NT - 1);
    STAGE(kt, (cur + 2) % 3);

    u16x8 a[4], b[4];
#pragma unroll
    for (int m = 0; m < 4; ++m) a[m] = *(const u16x8*)&As[cur][(arow + m * 16) * 32 + koff];
#pragma unroll
    for (int n = 0; n < 4; ++n) b[n] = *(const u16x8*)&Bs[cur][(brow + n * 16) * 32 + koff];
#pragma unroll
    for (int m = 0; m < 4; ++m)
#pragma unroll
      for (int n = 0; n < 4; ++n)
        asm("v_mfma_f32_16x16x32_bf16 %0, %1, %2, %0" : "+v"(acc[m][n]) : "v"(a[m]), "v"(b[n]));

    asm volatile("s_waitcnt vmcnt(4)" ::: "memory");
    BARF;
    cur = (cur + 1) % 3;
  }

  const int crow0 = m0 + wr * 64 + ((lane >> 4) << 2);
  const int ccol0 = n0 + wc * 64 + (lane & 15);
#pragma unroll
  for (int m = 0; m < 4; ++m) {
#pragma unroll
    for (int n = 0; n < 4; ++n) {
      const int col = ccol0 + n * 16;
      const float bia = bias[col];
#pragma unroll
      for (int r = 0; r < 4; ++r) {
        const int row = crow0 + m * 16 + r;
        const float v = acc[m][n][r];
        if (EPI == 3) {
          ((float*)Cv)[(size_t)row * ldc + col] = v + bia + xres[(size_t)row * ldx + col];
        } else if (EPI == 4) {
          ((u16*)Cv)[(size_t)row * ldc + col] = f2bf(gelu_exact(v + bia));
        } else {
          ((float*)Cv)[(size_t)row * ldc + col] = gelu_exact(v + bia);
        }
      }
    }
  }
  (void)scale;
}

// ---------------------------------------------------------------- launch
extern "C" void kernel_launch(void* const* d_in, const int* in_sizes, int n_in,
                              void* d_out, int out_size, void* d_ws, size_t ws_size,
                              hipStream_t stream) {
  const float* x     = (const float*)d_in[0];
  const float* w_qkv = (const float*)d_in[1];
  const float* b_qkv = (const float*)d_in[2];
  const float* w_msa = (const float*)d_in[3];
  const float* b_msa = (const float*)d_in[4];
  const float* ln_g  = (const float*)d_in[5];
  const float* ln_b  = (const float*)d_in[6];
  const float* w_h1  = (const float*)d_in[7];
  const float* b_h1  = (const float*)d_in[8];
  const float* w_h2  = (const float*)d_in[9];
  const float* b_h2  = (const float*)d_in[10];

  char* w = (char*)d_ws;
  u16*   qkv   = (u16*)(w + 0);            // 4096x3072 bf16
  u16*   sc    = (u16*)(w + 25165824);     // 4096x4096 bf16 (scores -> attn in place)
  u16*   lnb   = (u16*)(w + 58720256);     // 4096x1024 bf16 (ln1, then ln2)
  u16*   av    = (u16*)(w + 67108864);     // 4096x1024 bf16
  u16*   vT    = (u16*)(w + 75497472);     // 1024x4096 bf16
  float* enc1  = (float*)(w + 83886080);   // 4096x1024 f32
  u16*   part  = (u16*)(w + 83886080);     // 4x 4096x1024 bf16 split-K partials (dead before enc1)
  u16*   h1    = (u16*)(w + 100663296);    // 4096x512 bf16
  float* h2    = (float*)(w + 104857600);  // 4096x1024 f32
  u16*   wqkvT = (u16*)(w + 121634816);    // 3072x1024 bf16
  u16*   wmsaT = (u16*)(w + 127926272);    // 1024x1024 bf16
  u16*   wh1T  = (u16*)(w + 130023424);    // 512x1024 bf16
  u16*   wh2T  = (u16*)(w + 131072000);    // 1024x512 bf16
  (void)in_sizes; (void)n_in; (void)out_size; (void)ws_size;

  dim3 tb(32, 8);
  transpose4_f32_bf16<<<5120, tb, 0, stream>>>(w_qkv, wqkvT, w_msa, wmsaT,
                                               w_h1, wh1T, w_h2, wh2T);

  // ln1 = LN(x) -> bf16
  layernorm_bf16<<<4096, 256, 0, stream>>>(x, ln_g, ln_b, lnb);
  // qkv = ln1 @ w_qkv + b_qkv -> bf16   (256-tile, 12x16 = 192 blocks)
  gemm256<1><<<dim3(12, 16), 512, 0, stream>>>(lnb, 1024, wqkvT, 1024, qkv, 3072,
                                               b_qkv, 1.0f, 1024, 1, 0);
  // vT = v^T
  transpose_bf16<<<dim3(32, 128), tb, 0, stream>>>(qkv + 2048, 3072, vT, 4096);
  // scores = q @ k^T / 8 -> bf16   (16x16 = 256 blocks)
  gemm256<0><<<dim3(16, 16), 512, 0, stream>>>(qkv, 3072, qkv + 1024, 3072, sc, 4096,
                                               nullptr, 0.125f, 1024, 1, 0);
  // softmax rows (in place)
  softmax4096<<<4096, 256, 0, stream>>>(sc);
  // attn @ v: split-K=4 -> bf16 partials (grid 16x16 = 256 blocks), then reduce
  gemm256<2><<<dim3(16, 16), 512, 0, stream>>>(sc, 4096, vT, 4096, part, 1024,
                                               nullptr, 1.0f, 1024, 4, 4096ull * 1024ull);
  reduce_partials<<<2048, 256, 0, stream>>>(part, av);
  // enc1 = av @ w_msa + b_msa + x -> f32
  gemm_bt<3><<<dim3(8, 32), 256, 0, stream>>>(av, 1024, wmsaT, 1024, enc1, 1024,
                                              b_msa, x, 1024, 1.0f, 1024);
  // ln2 = LN(enc1) -> bf16
  layernorm_bf16<<<4096, 256, 0, stream>>>(enc1, ln_g, ln_b, lnb);
  // h1 = gelu(ln2 @ w_h1 + b_h1) -> bf16
  gemm_bt<4><<<dim3(4, 32), 256, 0, stream>>>(lnb, 1024, wh1T, 1024, h1, 512,
                                              b_h1, nullptr, 0, 1.0f, 1024);
  // h2 = gelu(h1 @ w_h2 + b_h2) -> f32
  gemm_bt<5><<<dim3(8, 32), 256, 0, stream>>>(h1, 512, wh2T, 512, h2, 1024,
                                              b_h2, nullptr, 0, 1.0f, 512);
  // out = enc1 + softmax(h2)
  final_softmax_add<<<4096, 256, 0, stream>>>(h2, enc1, (float*)d_out);
}